// Round 4
// baseline (711.643 us; speedup 1.0000x reference)
//
#include <hip/hip_runtime.h>
#include <hip/hip_cooperative_groups.h>

namespace cg = cooperative_groups;

#define MU_C     0.5f
#define C_NORM_C 8.0f
#define CG_IT    10
#define LRELU_C  0.2f
#define EPS_C    1e-12f

constexpr int BB = 16;   // batch
constexpr int KK = 16;   // neighbors
constexpr int EE = 6;    // embedding dim

// ws scalar slots (floats):
// sc[0]           : norm accumulator (sum deg^2 + sum w^2)
// sc[32+16i + b]  : gamma_i[b] = r_i . r_i
// sc[224+16i + b] : delta_i[b] = w_i . r_i
#define GAM 32
#define DEL 224

// f = LeakyReLU(W [x, emb] + b), padded (N,16,4). Block 0 zeroes scalar slots.
__global__ void k_feat(const float* __restrict__ x,
                       const float* __restrict__ emb,
                       const float* __restrict__ fcw,
                       const float* __restrict__ fcb,
                       float* __restrict__ ffp,
                       float* __restrict__ sc,
                       int N) {
    if (blockIdx.x == 0) {
        sc[threadIdx.x] = 0.f;
        sc[256 + threadIdx.x] = 0.f;
    }
    int n = blockIdx.x * blockDim.x + threadIdx.x;
    if (n >= N) return;
    float ev[EE];
#pragma unroll
    for (int j = 0; j < EE; ++j) ev[j] = emb[(size_t)n * EE + j];
    float g[3], w0[3];
#pragma unroll
    for (int f = 0; f < 3; ++f) {
        w0[f] = fcw[f * (EE + 1)];
        float s = fcb[f];
#pragma unroll
        for (int j = 0; j < EE; ++j) s += fcw[f * (EE + 1) + 1 + j] * ev[j];
        g[f] = s;
    }
    float o[BB * 4];
#pragma unroll
    for (int b = 0; b < BB; ++b) {
        float xv = x[(size_t)b * N + n];
#pragma unroll
        for (int f = 0; f < 3; ++f) {
            float v = g[f] + w0[f] * xv;
            o[b * 4 + f] = (v >= 0.f) ? v : LRELU_C * v;
        }
        o[b * 4 + 3] = 0.f;
    }
    float4* dst = (float4*)(ffp + (size_t)n * 64);
#pragma unroll
    for (int q = 0; q < 16; ++q) dst[q] = ((const float4*)o)[q];
}

// batch-parallel similarity weights; all 16 neighbor gathers issued up-front.
__global__ void k_weights(const int* __restrict__ nl,
                          const float* __restrict__ ffp,
                          const float* __restrict__ theta_p,
                          float* __restrict__ wl,
                          float* __restrict__ sc,
                          int N) {
    __shared__ float lds[4];
    int t = blockIdx.x * blockDim.x + threadIdx.x;
    int n = t >> 4, b = t & 15;
    float tp = 0.f;
    if (n < N) {
        float inv2t = 0.5f / theta_p[0];
        float4 fs = *(const float4*)(ffp + (size_t)n * 64 + b * 4);
        int kidx = nl[(size_t)n * KK + b];
        int ksafe = kidx < 0 ? 0 : kidx;
        int nbr[KK];
#pragma unroll
        for (int k = 0; k < KK; ++k) nbr[k] = __shfl(ksafe, k, 16);
        float4 fn[KK];
#pragma unroll
        for (int k = 0; k < KK; ++k)
            fn[k] = *(const float4*)(ffp + (size_t)nbr[k] * 64 + b * 4);
        float myw = 0.f;
#pragma unroll
        for (int k = 0; k < KK; ++k) {
            float d0 = fs.x - fn[k].x, d1 = fs.y - fn[k].y, d2 = fs.z - fn[k].z;
            float e = __expf(-(d0 * d0 + d1 * d1 + d2 * d2) * inv2t);
            e += __shfl_xor(e, 1, 16);
            e += __shfl_xor(e, 2, 16);
            e += __shfl_xor(e, 4, 16);
            e += __shfl_xor(e, 8, 16);
            if (k == b) myw = e * (1.f / BB);
        }
        if (kidx < 0) myw = 0.f;
        wl[(size_t)n * KK + b] = myw;
        float deg = myw, sw2 = myw * myw;
#pragma unroll
        for (int off = 1; off < 16; off <<= 1) {
            deg += __shfl_xor(deg, off, 16);
            sw2 += __shfl_xor(sw2, off, 16);
        }
        if (b == 0) tp = deg * deg + sw2;
    }
    tp += __shfl_xor(tp, 16, 64);
    tp += __shfl_xor(tp, 32, 64);
    int lane = threadIdx.x & 63, wid = threadIdx.x >> 6;
    if (lane == 0) lds[wid] = tp;
    __syncthreads();
    if (threadIdx.x == 0) {
        float ssum = 0.f;
        int nw = blockDim.x >> 6;
        for (int wv = 0; wv < nw; ++wv) ssum += lds[wv];
        atomicAdd(sc, ssum);
    }
}

// ---------- cooperative pipelined-CG path ----------

// thread holds part[8] for batch slots b = (t&1)*8 + j. Lane parity == t parity.
__device__ __forceinline__ void reduce16p8(const float part[8], float* lds, float* target) {
    float v[8];
#pragma unroll
    for (int j = 0; j < 8; ++j) {
        v[j] = part[j];
#pragma unroll
        for (int off = 32; off >= 2; off >>= 1) v[j] += __shfl_down(v[j], off);
    }
    int lane = threadIdx.x & 63, wid = threadIdx.x >> 6;
    if (lane < 2) {
#pragma unroll
        for (int j = 0; j < 8; ++j) lds[wid * 16 + lane * 8 + j] = v[j];
    }
    __syncthreads();
    if (threadIdx.x < 16) {
        float s = 0.f;
        int nw = blockDim.x >> 6;
        for (int wv = 0; wv < nw; ++wv) s += lds[wv * 16 + threadIdx.x];
        atomicAdd(target + threadIdx.x, s);
    }
}

// d = (I + musc*L) c for a float8 slice; nl/wl reloaded (L2-resident).
__device__ __forceinline__ void applyApair(const float* __restrict__ buf,
                                           const int* __restrict__ nl,
                                           const float* __restrict__ wl,
                                           int n, int h, float musc,
                                           float4 c0, float4 c1,
                                           float4& d0, float4& d1) {
    int idx[KK];
    float wr[KK];
#pragma unroll
    for (int qq = 0; qq < 4; ++qq) {
        int4 iv = ((const int4*)(nl + (size_t)n * KK))[qq];
        iv.x = iv.x < 0 ? 0 : iv.x;
        iv.y = iv.y < 0 ? 0 : iv.y;
        iv.z = iv.z < 0 ? 0 : iv.z;
        iv.w = iv.w < 0 ? 0 : iv.w;
        ((int4*)idx)[qq] = iv;
        ((float4*)wr)[qq] = ((const float4*)(wl + (size_t)n * KK))[qq];
    }
    float a[8] = {0.f, 0.f, 0.f, 0.f, 0.f, 0.f, 0.f, 0.f};
#pragma unroll
    for (int k = 0; k < KK; ++k) {
        size_t ob = (size_t)idx[k] * 16 + h * 8;
        float4 v0 = *(const float4*)(buf + ob);
        float4 v1 = *(const float4*)(buf + ob + 4);
        float wk = wr[k];
        a[0] += wk * (c0.x - v0.x); a[1] += wk * (c0.y - v0.y);
        a[2] += wk * (c0.z - v0.z); a[3] += wk * (c0.w - v0.w);
        a[4] += wk * (c1.x - v1.x); a[5] += wk * (c1.y - v1.y);
        a[6] += wk * (c1.z - v1.z); a[7] += wk * (c1.w - v1.w);
    }
    d0 = make_float4(c0.x + musc * a[0], c0.y + musc * a[1],
                     c0.z + musc * a[2], c0.w + musc * a[3]);
    d1 = make_float4(c1.x + musc * a[4], c1.y + musc * a[5],
                     c1.z + musc * a[6], c1.w + musc * a[7]);
}

// Ghysels-Vanroose pipelined CG, one cooperative kernel, one sync/iteration.
// Thread owns a contiguous float8 slice (node n, batch half h).
__global__ void __launch_bounds__(256, 2)
k_cg(const float* __restrict__ x,
     const int* __restrict__ nl,
     const float* __restrict__ wl,
     float* __restrict__ buf0,
     float* __restrict__ buf1,
     float* __restrict__ sc,
     float* __restrict__ out,
     int N) {
    cg::grid_group grid = cg::this_grid();
    __shared__ float ldsA[64], ldsB[64];
    int t = blockIdx.x * blockDim.x + threadIdx.x;
    int n = t >> 1, h = t & 1;
    bool act = t < N * 2;
    size_t o = (size_t)n * 16 + h * 8;

    float musc = MU_C * C_NORM_C / sqrtf(sc[0]);
    float4 zero = make_float4(0.f, 0.f, 0.f, 0.f);
    float4 r0 = zero, r1 = zero, w0 = zero, w1 = zero;
    float4 p0 = zero, p1 = zero, s0 = zero, s1 = zero;
    float4 z0 = zero, z1 = zero, xa = zero, xb = zero;

    if (act) {
        r0.x = x[(size_t)(h * 8 + 0) * N + n];
        r0.y = x[(size_t)(h * 8 + 1) * N + n];
        r0.z = x[(size_t)(h * 8 + 2) * N + n];
        r0.w = x[(size_t)(h * 8 + 3) * N + n];
        r1.x = x[(size_t)(h * 8 + 4) * N + n];
        r1.y = x[(size_t)(h * 8 + 5) * N + n];
        r1.z = x[(size_t)(h * 8 + 6) * N + n];
        r1.w = x[(size_t)(h * 8 + 7) * N + n];
        *(float4*)(buf0 + o) = r0;
        *(float4*)(buf0 + o + 4) = r1;
    }
    grid.sync();                                     // r visible
    if (act) {
        applyApair(buf0, nl, wl, n, h, musc, r0, r1, w0, w1);   // w0 = A r0
        *(float4*)(buf1 + o) = w0;
        *(float4*)(buf1 + o + 4) = w1;
    }

    float aprev[8], gprev[8];
    int cur = 1;                                     // buffer holding current w
    for (int i = 0; i < CG_IT; ++i) {
        float gp[8] = {0.f, 0.f, 0.f, 0.f, 0.f, 0.f, 0.f, 0.f};
        float dp[8] = {0.f, 0.f, 0.f, 0.f, 0.f, 0.f, 0.f, 0.f};
        if (act) {
            gp[0] = r0.x * r0.x; gp[1] = r0.y * r0.y; gp[2] = r0.z * r0.z; gp[3] = r0.w * r0.w;
            gp[4] = r1.x * r1.x; gp[5] = r1.y * r1.y; gp[6] = r1.z * r1.z; gp[7] = r1.w * r1.w;
            dp[0] = w0.x * r0.x; dp[1] = w0.y * r0.y; dp[2] = w0.z * r0.z; dp[3] = w0.w * r0.w;
            dp[4] = w1.x * r1.x; dp[5] = w1.y * r1.y; dp[6] = w1.z * r1.z; dp[7] = w1.w * r1.w;
        }
        reduce16p8(gp, ldsA, sc + GAM + 16 * i);
        reduce16p8(dp, ldsB, sc + DEL + 16 * i);
        grid.sync();                                 // slots done + prev w visible
        float4 q0 = zero, q1 = zero;
        if (i < CG_IT - 1 && act)
            applyApair(cur ? buf1 : buf0, nl, wl, n, h, musc, w0, w1, q0, q1);
        float al[8], be[8];
#pragma unroll
        for (int j = 0; j < 8; ++j) {
            float g = sc[GAM + 16 * i + h * 8 + j];
            float d = sc[DEL + 16 * i + h * 8 + j];
            float beta, denom;
            if (i == 0) { beta = 0.f; denom = d; }
            else {
                beta = g / (gprev[j] + EPS_C);
                denom = d - beta * g / aprev[j];
            }
            float alpha = g / (denom + EPS_C);
            al[j] = alpha; be[j] = beta;
            aprev[j] = alpha; gprev[j] = g;
        }
        if (act) {
            p0.x = r0.x + be[0] * p0.x; p0.y = r0.y + be[1] * p0.y;
            p0.z = r0.z + be[2] * p0.z; p0.w = r0.w + be[3] * p0.w;
            p1.x = r1.x + be[4] * p1.x; p1.y = r1.y + be[5] * p1.y;
            p1.z = r1.z + be[6] * p1.z; p1.w = r1.w + be[7] * p1.w;
            xa.x += al[0] * p0.x; xa.y += al[1] * p0.y;
            xa.z += al[2] * p0.z; xa.w += al[3] * p0.w;
            xb.x += al[4] * p1.x; xb.y += al[5] * p1.y;
            xb.z += al[6] * p1.z; xb.w += al[7] * p1.w;
            if (i < CG_IT - 1) {
                s0.x = w0.x + be[0] * s0.x; s0.y = w0.y + be[1] * s0.y;
                s0.z = w0.z + be[2] * s0.z; s0.w = w0.w + be[3] * s0.w;
                s1.x = w1.x + be[4] * s1.x; s1.y = w1.y + be[5] * s1.y;
                s1.z = w1.z + be[6] * s1.z; s1.w = w1.w + be[7] * s1.w;
                z0.x = q0.x + be[0] * z0.x; z0.y = q0.y + be[1] * z0.y;
                z0.z = q0.z + be[2] * z0.z; z0.w = q0.w + be[3] * z0.w;
                z1.x = q1.x + be[4] * z1.x; z1.y = q1.y + be[5] * z1.y;
                z1.z = q1.z + be[6] * z1.z; z1.w = q1.w + be[7] * z1.w;
                r0.x -= al[0] * s0.x; r0.y -= al[1] * s0.y;
                r0.z -= al[2] * s0.z; r0.w -= al[3] * s0.w;
                r1.x -= al[4] * s1.x; r1.y -= al[5] * s1.y;
                r1.z -= al[6] * s1.z; r1.w -= al[7] * s1.w;
                w0.x -= al[0] * z0.x; w0.y -= al[1] * z0.y;
                w0.z -= al[2] * z0.z; w0.w -= al[3] * z0.w;
                w1.x -= al[4] * z1.x; w1.y -= al[5] * z1.y;
                w1.z -= al[6] * z1.z; w1.w -= al[7] * z1.w;
                float* dst = cur ? buf0 : buf1;
                *(float4*)(dst + o) = w0;
                *(float4*)(dst + o + 4) = w1;
            } else {
                out[(size_t)(h * 8 + 0) * N + n] = xa.x;
                out[(size_t)(h * 8 + 1) * N + n] = xa.y;
                out[(size_t)(h * 8 + 2) * N + n] = xa.z;
                out[(size_t)(h * 8 + 3) * N + n] = xa.w;
                out[(size_t)(h * 8 + 4) * N + n] = xb.x;
                out[(size_t)(h * 8 + 5) * N + n] = xb.y;
                out[(size_t)(h * 8 + 6) * N + n] = xb.z;
                out[(size_t)(h * 8 + 7) * N + n] = xb.w;
            }
        }
        cur ^= 1;
    }
}

// ---------- fallback multi-kernel path (round-2 proven Chronopoulos CG) ----------

__device__ __forceinline__ void reduce16q4(float part[4], float* lds, float* target) {
#pragma unroll
    for (int j = 0; j < 4; ++j)
#pragma unroll
        for (int off = 32; off >= 4; off >>= 1) part[j] += __shfl_down(part[j], off);
    int lane = threadIdx.x & 63, wid = threadIdx.x >> 6;
    if (lane < 4) {
#pragma unroll
        for (int j = 0; j < 4; ++j) lds[wid * 16 + lane * 4 + j] = part[j];
    }
    __syncthreads();
    if (threadIdx.x < 16) {
        float ssum = 0.f;
        int nw = blockDim.x >> 6;
        for (int wv = 0; wv < nw; ++wv) ssum += lds[wv * 16 + threadIdx.x];
        atomicAdd(target + threadIdx.x, ssum);
    }
}

__global__ void k_init_f(const float* __restrict__ x, float* __restrict__ r,
                         float* __restrict__ sc, int N) {
    __shared__ float lds[64];
    int t = blockIdx.x * blockDim.x + threadIdx.x;
    float part[4] = {0.f, 0.f, 0.f, 0.f};
    if (t < N * 4) {
        int n = t >> 2, q = t & 3;
        float v0 = x[(size_t)(q * 4 + 0) * N + n];
        float v1 = x[(size_t)(q * 4 + 1) * N + n];
        float v2 = x[(size_t)(q * 4 + 2) * N + n];
        float v3 = x[(size_t)(q * 4 + 3) * N + n];
        part[0] = v0 * v0; part[1] = v1 * v1; part[2] = v2 * v2; part[3] = v3 * v3;
        *(float4*)(r + (size_t)n * 16 + q * 4) = make_float4(v0, v1, v2, v3);
    }
    reduce16q4(part, lds, sc + GAM);
}

__global__ void k_apply_f(const float* __restrict__ wl, const int* __restrict__ nl,
                          const float* __restrict__ r, float* __restrict__ p,
                          float* __restrict__ s, float* __restrict__ sc,
                          int iter, int N) {
    __shared__ float lds[64];
    int t = blockIdx.x * blockDim.x + threadIdx.x;
    float part[4] = {0.f, 0.f, 0.f, 0.f};
    if (t < N * 4) {
        int n = t >> 2, q = t & 3;
        float musc = MU_C * C_NORM_C / sqrtf(sc[0]);
        size_t o = (size_t)n * 16 + q * 4;
        float4 rq = *(const float4*)(r + o);
        int idx[KK];
        float wr[KK];
#pragma unroll
        for (int qq = 0; qq < 4; ++qq) {
            int4 iv = ((const int4*)(nl + (size_t)n * KK))[qq];
            iv.x = iv.x < 0 ? 0 : iv.x; iv.y = iv.y < 0 ? 0 : iv.y;
            iv.z = iv.z < 0 ? 0 : iv.z; iv.w = iv.w < 0 ? 0 : iv.w;
            ((int4*)idx)[qq] = iv;
            ((float4*)wr)[qq] = ((const float4*)(wl + (size_t)n * KK))[qq];
        }
        float a0 = 0.f, a1 = 0.f, a2 = 0.f, a3 = 0.f;
#pragma unroll
        for (int k = 0; k < KK; ++k) {
            float4 rn = *(const float4*)(r + (size_t)idx[k] * 16 + q * 4);
            float wk = wr[k];
            a0 += wk * (rq.x - rn.x); a1 += wk * (rq.y - rn.y);
            a2 += wk * (rq.z - rn.z); a3 += wk * (rq.w - rn.w);
        }
        float4 ar = make_float4(rq.x + musc * a0, rq.y + musc * a1,
                                rq.z + musc * a2, rq.w + musc * a3);
        part[0] = rq.x * ar.x; part[1] = rq.y * ar.y;
        part[2] = rq.z * ar.z; part[3] = rq.w * ar.w;
        float4 pn, sn;
        if (iter == 0) { pn = rq; sn = ar; }
        else {
            const float* g  = sc + GAM + 16 * iter;
            const float* gp = g - 16;
            float b0 = g[q * 4 + 0] / (gp[q * 4 + 0] + EPS_C);
            float b1 = g[q * 4 + 1] / (gp[q * 4 + 1] + EPS_C);
            float b2 = g[q * 4 + 2] / (gp[q * 4 + 2] + EPS_C);
            float b3 = g[q * 4 + 3] / (gp[q * 4 + 3] + EPS_C);
            float4 po = *(const float4*)(p + o);
            float4 so = *(const float4*)(s + o);
            pn.x = rq.x + b0 * po.x; pn.y = rq.y + b1 * po.y;
            pn.z = rq.z + b2 * po.z; pn.w = rq.w + b3 * po.w;
            sn.x = ar.x + b0 * so.x; sn.y = ar.y + b1 * so.y;
            sn.z = ar.z + b2 * so.z; sn.w = ar.w + b3 * so.w;
        }
        *(float4*)(p + o) = pn;
        *(float4*)(s + o) = sn;
    }
    reduce16q4(part, lds, sc + DEL + 16 * iter);
}

__global__ void k_upd_f(float* __restrict__ sc, float* __restrict__ x,
                        const float* __restrict__ p, const float* __restrict__ s,
                        float* __restrict__ r, float* __restrict__ out,
                        int iter, int N) {
    __shared__ float lds[64];
    int t = blockIdx.x * blockDim.x + threadIdx.x;
    float part[4] = {0.f, 0.f, 0.f, 0.f};
    if (t < N * 4) {
        int n = t >> 2, q = t & 3;
        float al[4];
#pragma unroll
        for (int j = 0; j < 4; ++j) {
            int b = q * 4 + j;
            float alpha = 0.f;
            for (int it = 0; it <= iter; ++it) {
                float g = sc[GAM + 16 * it + b];
                float d = sc[DEL + 16 * it + b];
                float denom;
                if (it == 0) denom = d;
                else {
                    float gpv = sc[GAM + 16 * (it - 1) + b];
                    float beta = g / (gpv + EPS_C);
                    denom = d - beta * g / alpha;
                }
                alpha = g / (denom + EPS_C);
            }
            al[j] = alpha;
        }
        size_t o = (size_t)n * 16 + q * 4;
        float4 pq = *(const float4*)(p + o);
        float4 xq;
        if (iter == 0) {
            xq = make_float4(al[0] * pq.x, al[1] * pq.y, al[2] * pq.z, al[3] * pq.w);
        } else {
            xq = *(const float4*)(x + o);
            xq.x += al[0] * pq.x; xq.y += al[1] * pq.y;
            xq.z += al[2] * pq.z; xq.w += al[3] * pq.w;
        }
        if (iter == CG_IT - 1) {
            out[(size_t)(q * 4 + 0) * N + n] = xq.x;
            out[(size_t)(q * 4 + 1) * N + n] = xq.y;
            out[(size_t)(q * 4 + 2) * N + n] = xq.z;
            out[(size_t)(q * 4 + 3) * N + n] = xq.w;
        } else {
            *(float4*)(x + o) = xq;
            float4 sq = *(const float4*)(s + o);
            float4 rq = *(const float4*)(r + o);
            rq.x -= al[0] * sq.x; rq.y -= al[1] * sq.y;
            rq.z -= al[2] * sq.z; rq.w -= al[3] * sq.w;
            *(float4*)(r + o) = rq;
            part[0] = rq.x * rq.x; part[1] = rq.y * rq.y;
            part[2] = rq.z * rq.z; part[3] = rq.w * rq.w;
        }
    }
    if (iter != CG_IT - 1)
        reduce16q4(part, lds, sc + GAM + 16 * (iter + 1));
}

extern "C" void kernel_launch(void* const* d_in, const int* in_sizes, int n_in,
                              void* d_out, int out_size, void* d_ws, size_t ws_size,
                              hipStream_t stream) {
    const float* x   = (const float*)d_in[0];
    const int*   nl  = (const int*)d_in[1];
    const float* emb = (const float*)d_in[2];
    const float* fcw = (const float*)d_in[3];
    const float* fcb = (const float*)d_in[4];
    const float* th  = (const float*)d_in[5];
    int N = in_sizes[1] / KK;   // 50000

    float* sc   = (float*)d_ws;               // 512 scalar slots
    float* wl   = sc + 512;                   // N*16 laplacian weights
    float* big  = wl + (size_t)N * 16;        // N*64 region
    float* ffp  = big;                        // (N,16,4) features (dead after weights)
    float* buf0 = big;                        // coop: w/r gather buffer
    float* buf1 = big + (size_t)N * 16;       // coop: w gather buffer
    float* outp = (float*)d_out;

    int G1 = (N + 255) / 256;
    int GW = (N * 16 + 255) / 256;
    int GC = (N * 2 + 255) / 256;             // 391 blocks x 256 threads
    int G4 = (N * 4 + 255) / 256;

    k_feat<<<G1, 256, 0, stream>>>(x, emb, fcw, fcb, ffp, sc, N);
    k_weights<<<GW, 256, 0, stream>>>(nl, ffp, th, wl, sc, N);

    void* args[] = {(void*)&x, (void*)&nl, (void*)&wl, (void*)&buf0, (void*)&buf1,
                    (void*)&sc, (void*)&outp, (void*)&N};
    hipError_t cerr = hipLaunchCooperativeKernel((const void*)k_cg, dim3(GC), dim3(256),
                                                 args, 0, stream);
    if (cerr != hipSuccess) {
        // proven multi-kernel fallback (slower, always correct)
        float* p_g  = big;
        float* s_g  = big + (size_t)N * 16;
        float* xk_g = big + (size_t)N * 32;
        float* r_g  = big + (size_t)N * 48;
        k_init_f<<<G4, 256, 0, stream>>>(x, r_g, sc, N);
        for (int i = 0; i < CG_IT; ++i) {
            k_apply_f<<<G4, 256, 0, stream>>>(wl, nl, r_g, p_g, s_g, sc, i, N);
            k_upd_f<<<G4, 256, 0, stream>>>(sc, xk_g, p_g, s_g, r_g, outp, i, N);
        }
    }
}